// Round 12
// baseline (446.495 us; speedup 1.0000x reference)
//
#include <hip/hip_runtime.h>

typedef __attribute__((ext_vector_type(8))) short bfrag;
typedef __attribute__((ext_vector_type(4))) float ffrag;

__device__ __forceinline__ ushort f2bf(float f) {
    union { float f; unsigned u; } v{f};
    unsigned r = v.u + 0x7fff + ((v.u >> 16) & 1);  // RNE
    return (ushort)(r >> 16);
}
__device__ __forceinline__ float bf2f(ushort u) {
    union { unsigned u; float f; } v{(unsigned)u << 16};
    return v.f;
}
__device__ __forceinline__ float bflo(unsigned u) {
    union { unsigned u; float f; } v{u << 16};
    return v.f;
}
__device__ __forceinline__ float bfhi(unsigned u) {
    union { unsigned u; float f; } v{u & 0xffff0000u};
    return v.f;
}

#define WDEC (1.f / 511.f)  // 9-bit fixed-point edge weight (err <= 1e-3 abs, 4x below bf16-feature noise)

#define NB 512
#define BSH 7
#define CH2 2048
#define CAP 4608   // bucket region capacity: Poisson mean 4096, sd 64 -> +8 sigma
#define PCAP 2432  // pool group capacity: mean 2048, sd ~45 -> +8 sigma

// ---------------- weight prep (bf16 transposed) + cursor init, one dispatch ----------------

__global__ __launch_bounds__(256) void wprep_zero(const float* __restrict__ Wb_in, const float* __restrict__ Wl_in,
                                                  const float* __restrict__ W_base, const float* __restrict__ W_local,
                                                  ushort* __restrict__ out,
                                                  int* __restrict__ bs_cur, int* __restrict__ ls_cur,
                                                  int* __restrict__ p_cur, int* __restrict__ psum) {
    const int bid = blockIdx.x;
    const int t = threadIdx.x;
    if (bid < 384) {
        int idx = bid * 256 + t;
        int mat = idx >> 14;
        int i = idx & 16383;
        int nn = i >> 7, kk = i & 127;
        const float* src;
        switch (mat) {
            case 0: src = Wb_in; break;
            case 1: src = Wl_in; break;
            case 2: src = W_base; break;
            case 3: src = W_base + 16384; break;
            case 4: src = W_local; break;
            default: src = W_local + 16384; break;
        }
        out[(size_t)mat * 16384 + i] = f2bf(src[kk * 128 + nn]);
    } else {
        int i = (bid - 384) * 256 + t;  // 0..8191
        if (i < 512) { bs_cur[i] = i * CAP; ls_cur[i] = i * CAP; }
        if (i < 64) p_cur[i] = i * PCAP;
        psum[i] = 0;  // pool_sum: 64*128 floats
    }
}

// ---------------- merged: bucket pass 1 (blocks <1024) + pool_scatter (blocks >=1024) ----------------
// Staged LDS radix: round-5 measured that direct global-atomic scatter costs 144 MB
// WRITE_SIZE (write-allocate on random 4-B RMW); staging keeps global writes coalesced.
// Staged entry packed to 4 B: src[15:0] | dst_local[22:16] | w9[31:23].

__global__ __launch_bounds__(512) void b1p(const int* __restrict__ b_src, const int* __restrict__ b_dst,
                                           const float* __restrict__ b_w, int* __restrict__ b_cur,
                                           int* __restrict__ b_staged,
                                           const int* __restrict__ l_src, const int* __restrict__ l_dst,
                                           const float* __restrict__ l_w, int* __restrict__ l_cur,
                                           int* __restrict__ l_staged,
                                           const int* __restrict__ memb_idx, const int* __restrict__ memb_gid,
                                           int* __restrict__ p_cursor, int* __restrict__ p_sorted) {
    __shared__ int cnt_s[NB], base_l[NB], base_g[NB], curs[NB];
    __shared__ int wtot[8];
    __shared__ int stage[CH2];
    __shared__ ushort bb[CH2];
    __shared__ int lhist[64], lbase[64], loff[1024];
    const int t = threadIdx.x;
    const int bid = blockIdx.x;
    if (bid < 1024) {
        const int g = bid >> 9;
        const int* src = g ? l_src : b_src;
        const int* dst = g ? l_dst : b_dst;
        const float* w = g ? l_w : b_w;
        int* bcursor = g ? l_cur : b_cur;
        int* staged = g ? l_staged : b_staged;
        const int base = (bid & 511) * CH2;
        cnt_s[t] = 0;
        __syncthreads();
#pragma unroll
        for (int u = 0; u < CH2 / 512; ++u) {
            int b = ((unsigned)dst[base + u * 512 + t]) >> BSH;
            atomicAdd(&cnt_s[b], 1);
        }
        __syncthreads();
        int v = cnt_s[t];
        int lane = t & 63, wid = t >> 6;
        int inc = v;
        for (int o = 1; o < 64; o <<= 1) { int x = __shfl_up(inc, o); if (lane >= o) inc += x; }
        if (lane == 63) wtot[wid] = inc;
        __syncthreads();
        int wpre = 0;
#pragma unroll
        for (int j = 0; j < 8; ++j) if (j < wid) wpre += wtot[j];
        int excl = wpre + inc - v;
        base_l[t] = excl;
        curs[t] = excl;
        base_g[t] = atomicAdd(&bcursor[t], v);
        __syncthreads();
#pragma unroll
        for (int u = 0; u < CH2 / 512; ++u) {
            int e = base + u * 512 + t;
            int d = dst[e];
            int b = ((unsigned)d) >> BSH;
            int p = atomicAdd(&curs[b], 1);
            unsigned wq = (unsigned)(w[e] * 511.f + 0.5f);
            stage[p] = (int)(((unsigned)src[e] & 0xffffu) | ((unsigned)(d & 127) << 16) | (wq << 23));
            bb[p] = (ushort)b;
        }
        __syncthreads();
        for (int i = t; i < CH2; i += 512) {
            int b = bb[i];
            staged[base_g[b] + (i - base_l[b])] = stage[i];
        }
    } else {
        // pool_scatter: counting-sort membership entries by gid (512 thr, 2 entries/thread)
        if (t < 64) lhist[t] = 0;
        __syncthreads();
        const int base = (bid - 1024) * 1024;
        int g[2], ix[2];
#pragma unroll
        for (int u = 0; u < 2; ++u) {
            int e = base + u * 512 + t;
            g[u] = memb_gid[e];
            ix[u] = memb_idx[e];
            loff[u * 512 + t] = atomicAdd(&lhist[g[u]], 1);
        }
        __syncthreads();
        if (t < 64) lbase[t] = atomicAdd(&p_cursor[t], lhist[t]);
        __syncthreads();
#pragma unroll
        for (int u = 0; u < 2; ++u) {
            int pos = lbase[g[u]] + loff[u * 512 + t];
            p_sorted[pos] = ix[u];
        }
    }
}

#define ASTRIDE 136  // ushort stride: 272B rows, 16B-aligned

// ---------------- merged: bucket pass 2 (blocks <1024) + input-projection GEMM (blocks >=1024) ----------------

__global__ __launch_bounds__(256) void b2g(const int* __restrict__ b_cur, const int* __restrict__ b_staged,
                                           int2* __restrict__ b_rng, int* __restrict__ b_edges,
                                           const int* __restrict__ l_cur, const int* __restrict__ l_staged,
                                           int2* __restrict__ l_rng, int* __restrict__ l_edges,
                                           const float* __restrict__ Ab, const float* __restrict__ Al,
                                           const ushort* __restrict__ Wt,
                                           const float* __restrict__ biasb, const float* __restrict__ biasl,
                                           ushort* __restrict__ Yb, ushort* __restrict__ Yl) {
    __shared__ __align__(16) char smem[52224];  // union: {seg|ord|segd} or {As|Bs}
    __shared__ int cnt[128], curs[128], wt2[2];
    const int t = threadIdx.x;
    const int bid = blockIdx.x;
    if (bid < 1024) {
        const int g = bid >> 9;
        const int b = bid & 511;
        const int* bcur = g ? l_cur : b_cur;
        const int* staged = g ? l_staged : b_staged;
        int2* rng = g ? l_rng : b_rng;
        int* edges = g ? l_edges : b_edges;
        const int s0 = b * CAP;
        int len = bcur[b] - s0;
        if (len > CAP) len = CAP;  // overflow guard (P ~ 1e-12)
        if (t < 128) cnt[t] = 0;
        __syncthreads();
        int* seg = (int*)smem;
        int* ord = (int*)(smem + CAP * 4);
        unsigned char* segd = (unsigned char*)(smem + CAP * 8);
        for (int i = t; i < len; i += 256) {
            int v = staged[s0 + i];
            int dl = (v >> 16) & 127;
            unsigned wq = ((unsigned)v) >> 23;
            seg[i] = (int)(((unsigned)v & 0xffffu) | (wq << 16));
            segd[i] = (unsigned char)dl;
            atomicAdd(&cnt[dl], 1);
        }
        __syncthreads();
        int v = 0, inc = 0;
        if (t < 128) {
            v = cnt[t];
            inc = v;
            for (int o = 1; o < 64; o <<= 1) { int x = __shfl_up(inc, o); if ((t & 63) >= o) inc += x; }
            if ((t & 63) == 63) wt2[t >> 6] = inc;
        }
        __syncthreads();
        if (t < 128) {
            int excl = inc - v + (t >= 64 ? wt2[0] : 0);
            curs[t] = excl;
            rng[b * 128 + t] = make_int2(s0 + excl, s0 + excl + v);
        }
        __syncthreads();
        for (int i = t; i < len; i += 256) {
            int p = atomicAdd(&curs[segd[i]], 1);
            ord[p] = seg[i];
        }
        __syncthreads();
        for (int i = t; i < len; i += 256)
            edges[s0 + i] = ord[i];
    } else {
        // input-projection GEMM (fp32 A -> bf16 Y), proven R8 tile
        ushort* As = (ushort*)smem;                       // 64 x ASTRIDE
        ushort* Bs = (ushort*)(smem + 64 * ASTRIDE * 2);  // 128 x ASTRIDE
        const int bid2 = bid - 1024;
        const int g = bid2 >> 10;
        const float* A = g ? Al : Ab;
        const ushort* W = Wt + (size_t)g * 16384;
        const float* bias = g ? biasl : biasb;
        ushort* Y = g ? Yl : Yb;
        const int r0 = (bid2 & 1023) * 64;

#pragma unroll
        for (int p = 0; p < 8; ++p) {
            int c = p * 256 + t;
            int row = c >> 5, o4 = (c & 31) * 4;
            float4 v = *(const float4*)(A + (size_t)(r0 + row) * 128 + o4);
            ushort4 u;
            u.x = f2bf(v.x); u.y = f2bf(v.y); u.z = f2bf(v.z); u.w = f2bf(v.w);
            *(ushort4*)&As[row * ASTRIDE + o4] = u;
        }
#pragma unroll
        for (int p = 0; p < 8; ++p) {
            int c = p * 256 + t;
            int n = c >> 4, o8 = (c & 15) * 8;
            *(uint4*)&Bs[n * ASTRIDE + o8] = *(const uint4*)(W + n * 128 + o8);
        }
        __syncthreads();

        const int lane = t & 63;
        const int w = t >> 6;
        const int wm = (w & 1) * 32;
        const int wn = (w >> 1) * 64;
        const int q = lane >> 4;
        const int l16 = lane & 15;

        ffrag acc[2][4];
#pragma unroll
        for (int mt = 0; mt < 2; ++mt)
#pragma unroll
            for (int nt = 0; nt < 4; ++nt) acc[mt][nt] = (ffrag){0.f, 0.f, 0.f, 0.f};

#pragma unroll
        for (int kc = 0; kc < 4; ++kc) {
            bfrag a[2], b[4];
#pragma unroll
            for (int mt = 0; mt < 2; ++mt)
                a[mt] = *(const bfrag*)&As[(wm + mt * 16 + l16) * ASTRIDE + kc * 32 + q * 8];
#pragma unroll
            for (int nt = 0; nt < 4; ++nt)
                b[nt] = *(const bfrag*)&Bs[(wn + nt * 16 + l16) * ASTRIDE + kc * 32 + q * 8];
#pragma unroll
            for (int mt = 0; mt < 2; ++mt)
#pragma unroll
                for (int nt = 0; nt < 4; ++nt)
                    acc[mt][nt] = __builtin_amdgcn_mfma_f32_16x16x32_bf16(a[mt], b[nt], acc[mt][nt], 0, 0, 0);
        }

        float bias_v[4];
#pragma unroll
        for (int nt = 0; nt < 4; ++nt) bias_v[nt] = bias[wn + nt * 16 + l16];
#pragma unroll
        for (int mt = 0; mt < 2; ++mt)
#pragma unroll
            for (int nt = 0; nt < 4; ++nt)
#pragma unroll
                for (int r = 0; r < 4; ++r) {
                    int row = r0 + wm + mt * 16 + q * 4 + r;
                    int col = wn + nt * 16 + l16;
                    float v = fmaxf(acc[mt][nt][r] + bias_v[nt], 0.f);
                    Y[(size_t)row * 128 + col] = f2bf(v);
                }
    }
}

// ---------------- layer GEMM standalone (bf16 A, alpha-mix, Bs LDS-staged) ----------------

template <bool MIX>
__global__ __launch_bounds__(256) void gemm_layer(const ushort* __restrict__ A, const ushort* __restrict__ A2,
                                                  const int* __restrict__ ridx,
                                                  const ushort* __restrict__ Wt, const float* __restrict__ bias,
                                                  ushort* __restrict__ Y) {
    __shared__ ushort As[64 * ASTRIDE];
    __shared__ ushort Bs[128 * ASTRIDE];
    const int tid = threadIdx.x;
    const int r0 = blockIdx.x * 64;

#pragma unroll
    for (int p = 0; p < 4; ++p) {
        int c = p * 256 + tid;
        int row = c >> 4, o8 = (c & 15) * 8;
        uint4 v = *(const uint4*)(A + (size_t)(r0 + row) * 128 + o8);
        if (MIX) {
            int rr = ridx[r0 + row];
            uint4 v2 = *(const uint4*)(A2 + (size_t)rr * 128 + o8);
            uint4 o;
            float x0, x1;
            x0 = 0.9f * bflo(v.x) + 0.1f * bflo(v2.x);
            x1 = 0.9f * bfhi(v.x) + 0.1f * bfhi(v2.x);
            o.x = (unsigned)f2bf(x0) | ((unsigned)f2bf(x1) << 16);
            x0 = 0.9f * bflo(v.y) + 0.1f * bflo(v2.y);
            x1 = 0.9f * bfhi(v.y) + 0.1f * bfhi(v2.y);
            o.y = (unsigned)f2bf(x0) | ((unsigned)f2bf(x1) << 16);
            x0 = 0.9f * bflo(v.z) + 0.1f * bflo(v2.z);
            x1 = 0.9f * bfhi(v.z) + 0.1f * bfhi(v2.z);
            o.z = (unsigned)f2bf(x0) | ((unsigned)f2bf(x1) << 16);
            x0 = 0.9f * bflo(v.w) + 0.1f * bflo(v2.w);
            x1 = 0.9f * bfhi(v.w) + 0.1f * bfhi(v2.w);
            o.w = (unsigned)f2bf(x0) | ((unsigned)f2bf(x1) << 16);
            v = o;
        }
        *(uint4*)&As[row * ASTRIDE + o8] = v;
    }
#pragma unroll
    for (int p = 0; p < 8; ++p) {
        int c = p * 256 + tid;
        int n = c >> 4, o8 = (c & 15) * 8;
        *(uint4*)&Bs[n * ASTRIDE + o8] = *(const uint4*)(Wt + n * 128 + o8);
    }
    __syncthreads();

    const int lane = tid & 63;
    const int w = tid >> 6;
    const int wm = (w & 1) * 32;
    const int wn = (w >> 1) * 64;
    const int q = lane >> 4;
    const int l16 = lane & 15;

    ffrag acc[2][4];
#pragma unroll
    for (int mt = 0; mt < 2; ++mt)
#pragma unroll
        for (int nt = 0; nt < 4; ++nt) acc[mt][nt] = (ffrag){0.f, 0.f, 0.f, 0.f};

#pragma unroll
    for (int kc = 0; kc < 4; ++kc) {
        bfrag a[2], b[4];
#pragma unroll
        for (int mt = 0; mt < 2; ++mt)
            a[mt] = *(const bfrag*)&As[(wm + mt * 16 + l16) * ASTRIDE + kc * 32 + q * 8];
#pragma unroll
        for (int nt = 0; nt < 4; ++nt)
            b[nt] = *(const bfrag*)&Bs[(wn + nt * 16 + l16) * ASTRIDE + kc * 32 + q * 8];
#pragma unroll
        for (int mt = 0; mt < 2; ++mt)
#pragma unroll
            for (int nt = 0; nt < 4; ++nt)
                acc[mt][nt] = __builtin_amdgcn_mfma_f32_16x16x32_bf16(a[mt], b[nt], acc[mt][nt], 0, 0, 0);
    }

    float bias_v[4];
#pragma unroll
    for (int nt = 0; nt < 4; ++nt) bias_v[nt] = bias[wn + nt * 16 + l16];
#pragma unroll
    for (int mt = 0; mt < 2; ++mt)
#pragma unroll
        for (int nt = 0; nt < 4; ++nt)
#pragma unroll
            for (int r = 0; r < 4; ++r) {
                int row = r0 + wm + mt * 16 + q * 4 + r;
                int col = wn + nt * 16 + l16;
                float v = fmaxf(acc[mt][nt][r] + bias_v[nt], 0.f);
                Y[(size_t)row * 128 + col] = f2bf(v);
            }
}

// ---------------- merged: layer GEMM (blocks < ngemm) + single-graph SpMM (blocks >= ngemm) ----------------
// spmm2 leaves MfmaUtil=0 / VALU 45% idle; the layer GEMMs are pure-MFMA. m114: MFMA-waves and
// memory-waves co-schedule at time ~= max, not sum -> pair each layer GEMM with the OTHER
// graph's (independent) SpMM half in one dispatch. GEMM part drops the Bs LDS stage (B frags
// direct from the L1-resident 32 KB weight matrix, proven in round 2) so static LDS = 17.4 KB
// -> spmm blocks keep the 8-block/CU wave cap. GEMM blocks first so they overlap from t=0.
// SpMM body = round-9 proven form (plain int4 edge loads; NT reverted: round-11 measured +2.6 MB
// FETCH / +2.6 us from broken line coalescing).

#define PROC8(pA, pB)                                                                          \
    {                                                                                          \
        ushort4 v0 = *(const ushort4*)(X + ((size_t)((unsigned)pA.x & 0xffffu) << 7) + f);     \
        ushort4 v1 = *(const ushort4*)(X + ((size_t)((unsigned)pA.y & 0xffffu) << 7) + f);     \
        ushort4 v2 = *(const ushort4*)(X + ((size_t)((unsigned)pA.z & 0xffffu) << 7) + f);     \
        ushort4 v3 = *(const ushort4*)(X + ((size_t)((unsigned)pA.w & 0xffffu) << 7) + f);     \
        ushort4 v4 = *(const ushort4*)(X + ((size_t)((unsigned)pB.x & 0xffffu) << 7) + f);     \
        ushort4 v5 = *(const ushort4*)(X + ((size_t)((unsigned)pB.y & 0xffffu) << 7) + f);     \
        ushort4 v6 = *(const ushort4*)(X + ((size_t)((unsigned)pB.z & 0xffffu) << 7) + f);     \
        ushort4 v7 = *(const ushort4*)(X + ((size_t)((unsigned)pB.w & 0xffffu) << 7) + f);     \
        float w0 = (float)((unsigned)pA.x >> 16) * WDEC;                                       \
        float w1 = (float)((unsigned)pA.y >> 16) * WDEC;                                       \
        float w2 = (float)((unsigned)pA.z >> 16) * WDEC;                                       \
        float w3 = (float)((unsigned)pA.w >> 16) * WDEC;                                       \
        float w4 = (float)((unsigned)pB.x >> 16) * WDEC;                                       \
        float w5 = (float)((unsigned)pB.y >> 16) * WDEC;                                       \
        float w6 = (float)((unsigned)pB.z >> 16) * WDEC;                                       \
        float w7 = (float)((unsigned)pB.w >> 16) * WDEC;                                       \
        a0 += w0 * bf2f(v0.x) + w1 * bf2f(v1.x) + w2 * bf2f(v2.x) + w3 * bf2f(v3.x)            \
            + w4 * bf2f(v4.x) + w5 * bf2f(v5.x) + w6 * bf2f(v6.x) + w7 * bf2f(v7.x);           \
        a1 += w0 * bf2f(v0.y) + w1 * bf2f(v1.y) + w2 * bf2f(v2.y) + w3 * bf2f(v3.y)            \
            + w4 * bf2f(v4.y) + w5 * bf2f(v5.y) + w6 * bf2f(v6.y) + w7 * bf2f(v7.y);           \
        a2 += w0 * bf2f(v0.z) + w1 * bf2f(v1.z) + w2 * bf2f(v2.z) + w3 * bf2f(v3.z)            \
            + w4 * bf2f(v4.z) + w5 * bf2f(v5.z) + w6 * bf2f(v6.z) + w7 * bf2f(v7.z);           \
        a3 += w0 * bf2f(v0.w) + w1 * bf2f(v1.w) + w2 * bf2f(v2.w) + w3 * bf2f(v3.w)            \
            + w4 * bf2f(v4.w) + w5 * bf2f(v5.w) + w6 * bf2f(v6.w) + w7 * bf2f(v7.w);           \
    }

template <bool MIX>
__global__ __launch_bounds__(256) void sg(int ngemm,
                                          const int2* __restrict__ rng, const int* __restrict__ edges,
                                          const ushort* __restrict__ X, ushort* __restrict__ Y,
                                          const ushort* __restrict__ GA, const ushort* __restrict__ GA2,
                                          const int* __restrict__ ridx, const ushort* __restrict__ GW,
                                          const float* __restrict__ Gbias, ushort* __restrict__ GY) {
    __shared__ ushort As[64 * ASTRIDE];  // 17.4 KB: spmm blocks keep 8 blk/CU (139 KB < 160)
    const int t = threadIdx.x;
    const int bid = blockIdx.x;
    if (bid < ngemm) {
        // ---- layer GEMM tile, B direct from global ----
        const int r0 = bid * 64;
#pragma unroll
        for (int p = 0; p < 4; ++p) {
            int c = p * 256 + t;
            int row = c >> 4, o8 = (c & 15) * 8;
            uint4 v = *(const uint4*)(GA + (size_t)(r0 + row) * 128 + o8);
            if (MIX) {
                int rr = ridx[r0 + row];
                uint4 v2 = *(const uint4*)(GA2 + (size_t)rr * 128 + o8);
                uint4 o;
                float x0, x1;
                x0 = 0.9f * bflo(v.x) + 0.1f * bflo(v2.x);
                x1 = 0.9f * bfhi(v.x) + 0.1f * bfhi(v2.x);
                o.x = (unsigned)f2bf(x0) | ((unsigned)f2bf(x1) << 16);
                x0 = 0.9f * bflo(v.y) + 0.1f * bflo(v2.y);
                x1 = 0.9f * bfhi(v.y) + 0.1f * bfhi(v2.y);
                o.y = (unsigned)f2bf(x0) | ((unsigned)f2bf(x1) << 16);
                x0 = 0.9f * bflo(v.z) + 0.1f * bflo(v2.z);
                x1 = 0.9f * bfhi(v.z) + 0.1f * bfhi(v2.z);
                o.z = (unsigned)f2bf(x0) | ((unsigned)f2bf(x1) << 16);
                x0 = 0.9f * bflo(v.w) + 0.1f * bflo(v2.w);
                x1 = 0.9f * bfhi(v.w) + 0.1f * bfhi(v2.w);
                o.w = (unsigned)f2bf(x0) | ((unsigned)f2bf(x1) << 16);
                v = o;
            }
            *(uint4*)&As[row * ASTRIDE + o8] = v;
        }
        __syncthreads();

        const int lane = t & 63;
        const int w = t >> 6;
        const int wm = (w & 1) * 32;
        const int wn = (w >> 1) * 64;
        const int q = lane >> 4;
        const int l16 = lane & 15;

        ffrag acc[2][4];
#pragma unroll
        for (int mt = 0; mt < 2; ++mt)
#pragma unroll
            for (int nt = 0; nt < 4; ++nt) acc[mt][nt] = (ffrag){0.f, 0.f, 0.f, 0.f};

#pragma unroll
        for (int kc = 0; kc < 4; ++kc) {
            bfrag a[2], b[4];
#pragma unroll
            for (int mt = 0; mt < 2; ++mt)
                a[mt] = *(const bfrag*)&As[(wm + mt * 16 + l16) * ASTRIDE + kc * 32 + q * 8];
#pragma unroll
            for (int nt = 0; nt < 4; ++nt)
                b[nt] = *(const bfrag*)(GW + (size_t)(wn + nt * 16 + l16) * 128 + kc * 32 + q * 8);
#pragma unroll
            for (int mt = 0; mt < 2; ++mt)
#pragma unroll
                for (int nt = 0; nt < 4; ++nt)
                    acc[mt][nt] = __builtin_amdgcn_mfma_f32_16x16x32_bf16(a[mt], b[nt], acc[mt][nt], 0, 0, 0);
        }

        float bias_v[4];
#pragma unroll
        for (int nt = 0; nt < 4; ++nt) bias_v[nt] = Gbias[wn + nt * 16 + l16];
#pragma unroll
        for (int mt = 0; mt < 2; ++mt)
#pragma unroll
            for (int nt = 0; nt < 4; ++nt)
#pragma unroll
                for (int r = 0; r < 4; ++r) {
                    int row = r0 + wm + mt * 16 + q * 4 + r;
                    int col = wn + nt * 16 + l16;
                    float v = fmaxf(acc[mt][nt][r] + bias_v[nt], 0.f);
                    GY[(size_t)row * 128 + col] = f2bf(v);
                }
    } else {
        // ---- SpMM: half-wave per dst node (round-9 proven form) ----
        int node = (((bid - ngemm) * 256) + t) >> 5;
        int lane = t & 31;
        int2 r = rng[node];
        int s0 = r.x;
        int s1 = r.y;
        const int f = lane * 4;
        float a0 = 0.f, a1 = 0.f, a2 = 0.f, a3 = 0.f;
        int e = s0;
        for (; e < s1 && (e & 3); ++e) {
            unsigned pe = (unsigned)edges[e];
            float w = (float)(pe >> 16) * WDEC;
            ushort4 v = *(const ushort4*)(X + ((size_t)(pe & 0xffffu) << 7) + f);
            a0 += w * bf2f(v.x); a1 += w * bf2f(v.y); a2 += w * bf2f(v.z); a3 += w * bf2f(v.w);
        }
        if (e + 8 <= s1) {
            int4 pA = *(const int4*)(edges + e);
            int4 pB = *(const int4*)(edges + e + 4);
            for (; e + 16 <= s1; e += 8) {
                int4 nA = *(const int4*)(edges + e + 8);   // prefetch next iter's edges
                int4 nB = *(const int4*)(edges + e + 12);
                PROC8(pA, pB);
                pA = nA;
                pB = nB;
            }
            PROC8(pA, pB);
            e += 8;
        }
        for (; e + 4 <= s1; e += 4) {
            int4 pA = *(const int4*)(edges + e);
            ushort4 v0 = *(const ushort4*)(X + ((size_t)((unsigned)pA.x & 0xffffu) << 7) + f);
            ushort4 v1 = *(const ushort4*)(X + ((size_t)((unsigned)pA.y & 0xffffu) << 7) + f);
            ushort4 v2 = *(const ushort4*)(X + ((size_t)((unsigned)pA.z & 0xffffu) << 7) + f);
            ushort4 v3 = *(const ushort4*)(X + ((size_t)((unsigned)pA.w & 0xffffu) << 7) + f);
            float w0 = (float)((unsigned)pA.x >> 16) * WDEC;
            float w1 = (float)((unsigned)pA.y >> 16) * WDEC;
            float w2 = (float)((unsigned)pA.z >> 16) * WDEC;
            float w3 = (float)((unsigned)pA.w >> 16) * WDEC;
            a0 += w0 * bf2f(v0.x) + w1 * bf2f(v1.x) + w2 * bf2f(v2.x) + w3 * bf2f(v3.x);
            a1 += w0 * bf2f(v0.y) + w1 * bf2f(v1.y) + w2 * bf2f(v2.y) + w3 * bf2f(v3.y);
            a2 += w0 * bf2f(v0.z) + w1 * bf2f(v1.z) + w2 * bf2f(v2.z) + w3 * bf2f(v3.z);
            a3 += w0 * bf2f(v0.w) + w1 * bf2f(v1.w) + w2 * bf2f(v2.w) + w3 * bf2f(v3.w);
        }
        for (; e < s1; ++e) {
            unsigned pe = (unsigned)edges[e];
            float w = (float)(pe >> 16) * WDEC;
            ushort4 v = *(const ushort4*)(X + ((size_t)(pe & 0xffffu) << 7) + f);
            a0 += w * bf2f(v.x); a1 += w * bf2f(v.y); a2 += w * bf2f(v.z); a3 += w * bf2f(v.w);
        }
        ushort4 o;
        o.x = f2bf(a0);
        o.y = f2bf(a1);
        o.z = f2bf(a2);
        o.w = f2bf(a3);
        *(ushort4*)(Y + (size_t)node * 128 + f) = o;
    }
}

// ---------------- pooling: segment sums over gid-sorted entries (fixed-capacity regions) ----------------

__global__ __launch_bounds__(256) void pool_accum(const int* __restrict__ p_cur, const int* __restrict__ sorted_idx,
                                                  const ushort* __restrict__ X, float* __restrict__ gsum) {
    const int g = blockIdx.x >> 5;
    const int sgm = blockIdx.x & 31;
    const int gs = g * PCAP;
    const int cnt = p_cur[g] - gs;
    const int e_begin = gs + ((cnt * sgm) >> 5);
    const int e_end = gs + ((cnt * (sgm + 1)) >> 5);
    const int t = threadIdx.x;
    const int fp = t & 63;
    const int sub = t >> 6;
    float ax = 0.f, ay = 0.f;
#pragma unroll 4
    for (int e = e_begin + sub; e < e_end; e += 4) {
        int idx = sorted_idx[e];
        ushort2 u = *(const ushort2*)(X + (size_t)idx * 128 + fp * 2);
        ax += bf2f(u.x);
        ay += bf2f(u.y);
    }
    __shared__ float sx[256], sy[256];
    sx[t] = ax;
    sy[t] = ay;
    __syncthreads();
    if (t < 64) {
        atomicAdd(&gsum[g * 128 + fp * 2 + 0], sx[t] + sx[t + 64] + sx[t + 128] + sx[t + 192]);
        atomicAdd(&gsum[g * 128 + fp * 2 + 1], sy[t] + sy[t + 64] + sy[t + 128] + sy[t + 192]);
    }
}

// ---------------- final: out = (gsum/cnt) @ Wp + bp, 64x2 ----------------

__global__ __launch_bounds__(128) void final_kernel(const float* __restrict__ gsum, const int* __restrict__ p_cur,
                                                    const float* __restrict__ Wp, const float* __restrict__ bp,
                                                    float* __restrict__ out) {
    int t = threadIdx.x;
    int g = t >> 1;
    int o = t & 1;
    float cnt = (float)(p_cur[g] - g * PCAP);
    float inv = 1.f / fmaxf(cnt, 1.f);
    float acc = bp[o];
    for (int f = 0; f < 128; ++f) acc += gsum[g * 128 + f] * inv * Wp[f * 2 + o];
    out[g * 2 + o] = acc;
}

// ---------------- launch ----------------

extern "C" void kernel_launch(void* const* d_in, const int* in_sizes, int n_in,
                              void* d_out, int out_size, void* d_ws, size_t ws_size,
                              hipStream_t stream) {
    const float* x              = (const float*)d_in[0];
    const int*   edge_index     = (const int*)d_in[1];
    const float* edge_weight    = (const float*)d_in[2];
    const float* local_x0       = (const float*)d_in[3];
    const int*   copy2orig      = (const int*)d_in[4];
    const int*   local_adj_idx  = (const int*)d_in[5];
    const float* local_adj_val  = (const float*)d_in[6];
    const int*   memb_idx       = (const int*)d_in[7];
    const int*   memb_gid       = (const int*)d_in[8];
    const float* Wb_in          = (const float*)d_in[10];
    const float* bb_in          = (const float*)d_in[11];
    const float* Wl_in          = (const float*)d_in[12];
    const float* bl_in          = (const float*)d_in[13];
    const float* W_base         = (const float*)d_in[14];
    const float* b_base         = (const float*)d_in[15];
    const float* W_local        = (const float*)d_in[16];
    const float* b_local        = (const float*)d_in[17];
    const float* Wp             = (const float*)d_in[18];
    const float* bp             = (const float*)d_in[19];
    float* out = (float*)d_out;

    constexpr int N = 65536, M = 65536, E = 1048576, EL = 1048576, K = 131072, H = 128;

    char* wsb = (char*)d_ws;
    size_t off = 0;
    auto alloc = [&](size_t bytes) -> char* {
        char* p = wsb + off;
        off += (bytes + 255) & ~(size_t)255;
        return p;
    };
    int2*   bs_rng   = (int2*)alloc((size_t)N * 8);
    int*    bs_edges = (int*)alloc((size_t)NB * CAP * 4 + 64);
    int*    bs_stage = (int*)alloc((size_t)NB * CAP * 4);
    int*    bs_cur   = (int*)alloc(NB * 4);
    int2*   ls_rng   = (int2*)alloc((size_t)M * 8);
    int*    ls_edges = (int*)alloc((size_t)NB * CAP * 4 + 64);
    int*    ls_stage = (int*)alloc((size_t)NB * CAP * 4);
    int*    ls_cur   = (int*)alloc(NB * 4);
    ushort* bufA     = (ushort*)alloc((size_t)N * H * 2);
    ushort* bufB     = (ushort*)alloc((size_t)M * H * 2);
    ushort* bufC     = (ushort*)alloc((size_t)N * H * 2);
    ushort* bufD     = (ushort*)alloc((size_t)M * H * 2);
    ushort* wt       = (ushort*)alloc((size_t)6 * 16384 * 2);
    int*    p_cursor = (int*)alloc(64 * 4);
    int*    p_sorted = (int*)alloc((size_t)64 * PCAP * 4);
    float*  pool_sum = (float*)alloc(64 * 128 * 4);

    const int* b_src = edge_index;
    const int* b_dst = edge_index + E;
    const int* l_src = local_adj_idx;
    const int* l_dst = local_adj_idx + EL;

    // weight prep + fixed-capacity cursor init (one dispatch)
    wprep_zero<<<416, 256, 0, stream>>>(Wb_in, Wl_in, W_base, W_local, wt,
                                        bs_cur, ls_cur, p_cursor, (int*)pool_sum);

    // bucket pass 1 (both graphs, 4-B staged entries) || pool counting-sort scatter
    b1p<<<1152, 512, 0, stream>>>(b_src, b_dst, edge_weight, bs_cur, bs_stage,
                                  l_src, l_dst, local_adj_val, ls_cur, ls_stage,
                                  memb_idx, memb_gid, p_cursor, p_sorted);

    // bucket pass 2 (single LDS pass) || input-projection GEMMs (A, B)
    b2g<<<3072, 256, 0, stream>>>(bs_cur, bs_stage, bs_rng, bs_edges,
                                  ls_cur, ls_stage, ls_rng, ls_edges,
                                  x, local_x0, wt, bb_in, bl_in, bufA, bufB);

    // layer chain with GEMM||SpMM overlap (all pairs write-disjoint; deps via dispatch order):
    //   base0 spmm          : A -> C
    //   M1: local0 (B->D)   || gemm_f0 (C -> A)
    //   M2: base1 (A->C)    || gemm_t0 (D, mix A -> B)
    //   M3: local1 (B->D)   || gemm_f1 (C -> A)
    //   gemm_t1             : D, mix A -> B
    sg<false><<<8192, 256, 0, stream>>>(0, bs_rng, bs_edges, bufA, bufC,
                                        nullptr, nullptr, nullptr, nullptr, nullptr, nullptr);
    sg<false><<<9216, 256, 0, stream>>>(1024, ls_rng, ls_edges, bufB, bufD,
                                        bufC, nullptr, nullptr, wt + (size_t)2 * 16384, b_base, bufA);
    sg<true><<<9216, 256, 0, stream>>>(1024, bs_rng, bs_edges, bufA, bufC,
                                       bufD, bufA, copy2orig, wt + (size_t)4 * 16384, b_local, bufB);
    sg<false><<<9216, 256, 0, stream>>>(1024, ls_rng, ls_edges, bufB, bufD,
                                        bufC, nullptr, nullptr, wt + (size_t)3 * 16384, b_base + H, bufA);
    gemm_layer<true><<<1024, 256, 0, stream>>>(bufD, bufA, copy2orig,
                                               wt + (size_t)5 * 16384, b_local + H, bufB);

    // pooling + final projection
    pool_accum<<<64 * 32, 256, 0, stream>>>(p_cursor, p_sorted, bufB, pool_sum);
    final_kernel<<<1, 128, 0, stream>>>(pool_sum, p_cursor, Wp, bp, out);
}

// Round 14
// 383.503 us; speedup vs baseline: 1.1643x; 1.1643x over previous
//
#include <hip/hip_runtime.h>

typedef __attribute__((ext_vector_type(8))) short bfrag;
typedef __attribute__((ext_vector_type(4))) float ffrag;

__device__ __forceinline__ ushort f2bf(float f) {
    union { float f; unsigned u; } v{f};
    unsigned r = v.u + 0x7fff + ((v.u >> 16) & 1);  // RNE
    return (ushort)(r >> 16);
}
__device__ __forceinline__ float bf2f(ushort u) {
    union { unsigned u; float f; } v{(unsigned)u << 16};
    return v.f;
}
__device__ __forceinline__ float bflo(unsigned u) {
    union { unsigned u; float f; } v{u << 16};
    return v.f;
}
__device__ __forceinline__ float bfhi(unsigned u) {
    union { unsigned u; float f; } v{u & 0xffff0000u};
    return v.f;
}

#define WDEC (1.f / 511.f)  // 9-bit fixed-point edge weight (err <= 1e-3 abs, 4x below bf16-feature noise)

#define NB 512
#define BSH 7
#define CH2 2048
#define CAP 4608   // bucket region capacity: Poisson mean 4096, sd 64 -> +8 sigma
#define PCAP 2432  // pool group capacity: mean 2048, sd ~45 -> +8 sigma

// ---------------- weight prep (bf16 transposed) + cursor init, one dispatch ----------------
// Fixed-capacity bucket regions: dst is uniform, so bucket counts are Poisson(4096).
// Pre-setting cursors to b*CAP removes the histogram + scan pre-pass entirely.

__global__ __launch_bounds__(256) void wprep_zero(const float* __restrict__ Wb_in, const float* __restrict__ Wl_in,
                                                  const float* __restrict__ W_base, const float* __restrict__ W_local,
                                                  ushort* __restrict__ out,
                                                  int* __restrict__ bs_cur, int* __restrict__ ls_cur,
                                                  int* __restrict__ p_cur, int* __restrict__ psum) {
    const int bid = blockIdx.x;
    const int t = threadIdx.x;
    if (bid < 384) {
        int idx = bid * 256 + t;
        int mat = idx >> 14;
        int i = idx & 16383;
        int nn = i >> 7, kk = i & 127;
        const float* src;
        switch (mat) {
            case 0: src = Wb_in; break;
            case 1: src = Wl_in; break;
            case 2: src = W_base; break;
            case 3: src = W_base + 16384; break;
            case 4: src = W_local; break;
            default: src = W_local + 16384; break;
        }
        out[(size_t)mat * 16384 + i] = f2bf(src[kk * 128 + nn]);
    } else {
        int i = (bid - 384) * 256 + t;  // 0..8191
        if (i < 512) { bs_cur[i] = i * CAP; ls_cur[i] = i * CAP; }
        if (i < 64) p_cur[i] = i * PCAP;
        psum[i] = 0;  // pool_sum: 64*128 floats
    }
}

// ---------------- merged: bucket pass 1 (blocks <1024) + pool_scatter (blocks >=1024) ----------------
// Staged LDS radix: round-5 measured that direct global-atomic hist/scatter costs 144 MB
// WRITE_SIZE (write-allocate on random 4-B RMW); staging keeps global writes coalesced.
// Staged entry packed to 4 B: src[15:0] | dst_local[22:16] | w9[31:23].

__global__ __launch_bounds__(512) void b1p(const int* __restrict__ b_src, const int* __restrict__ b_dst,
                                           const float* __restrict__ b_w, int* __restrict__ b_cur,
                                           int* __restrict__ b_staged,
                                           const int* __restrict__ l_src, const int* __restrict__ l_dst,
                                           const float* __restrict__ l_w, int* __restrict__ l_cur,
                                           int* __restrict__ l_staged,
                                           const int* __restrict__ memb_idx, const int* __restrict__ memb_gid,
                                           int* __restrict__ p_cursor, int* __restrict__ p_sorted) {
    __shared__ int cnt_s[NB], base_l[NB], base_g[NB], curs[NB];
    __shared__ int wtot[8];
    __shared__ int stage[CH2];
    __shared__ ushort bb[CH2];
    __shared__ int lhist[64], lbase[64], loff[1024];
    const int t = threadIdx.x;
    const int bid = blockIdx.x;
    if (bid < 1024) {
        const int g = bid >> 9;
        const int* src = g ? l_src : b_src;
        const int* dst = g ? l_dst : b_dst;
        const float* w = g ? l_w : b_w;
        int* bcursor = g ? l_cur : b_cur;
        int* staged = g ? l_staged : b_staged;
        const int base = (bid & 511) * CH2;
        cnt_s[t] = 0;
        __syncthreads();
#pragma unroll
        for (int u = 0; u < CH2 / 512; ++u) {
            int b = ((unsigned)dst[base + u * 512 + t]) >> BSH;
            atomicAdd(&cnt_s[b], 1);
        }
        __syncthreads();
        int v = cnt_s[t];
        int lane = t & 63, wid = t >> 6;
        int inc = v;
        for (int o = 1; o < 64; o <<= 1) { int x = __shfl_up(inc, o); if (lane >= o) inc += x; }
        if (lane == 63) wtot[wid] = inc;
        __syncthreads();
        int wpre = 0;
#pragma unroll
        for (int j = 0; j < 8; ++j) if (j < wid) wpre += wtot[j];
        int excl = wpre + inc - v;
        base_l[t] = excl;
        curs[t] = excl;
        base_g[t] = atomicAdd(&bcursor[t], v);
        __syncthreads();
#pragma unroll
        for (int u = 0; u < CH2 / 512; ++u) {
            int e = base + u * 512 + t;
            int d = dst[e];
            int b = ((unsigned)d) >> BSH;
            int p = atomicAdd(&curs[b], 1);
            unsigned wq = (unsigned)(w[e] * 511.f + 0.5f);
            stage[p] = (int)(((unsigned)src[e] & 0xffffu) | ((unsigned)(d & 127) << 16) | (wq << 23));
            bb[p] = (ushort)b;
        }
        __syncthreads();
        for (int i = t; i < CH2; i += 512) {
            int b = bb[i];
            staged[base_g[b] + (i - base_l[b])] = stage[i];
        }
    } else {
        // pool_scatter: counting-sort membership entries by gid (512 thr, 2 entries/thread)
        if (t < 64) lhist[t] = 0;
        __syncthreads();
        const int base = (bid - 1024) * 1024;
        int g[2], ix[2];
#pragma unroll
        for (int u = 0; u < 2; ++u) {
            int e = base + u * 512 + t;
            g[u] = memb_gid[e];
            ix[u] = memb_idx[e];
            loff[u * 512 + t] = atomicAdd(&lhist[g[u]], 1);
        }
        __syncthreads();
        if (t < 64) lbase[t] = atomicAdd(&p_cursor[t], lhist[t]);
        __syncthreads();
#pragma unroll
        for (int u = 0; u < 2; ++u) {
            int pos = lbase[g[u]] + loff[u * 512 + t];
            p_sorted[pos] = ix[u];
        }
    }
}

#define ASTRIDE 136  // ushort stride: 272B rows, 16B-aligned

// ---------------- merged: bucket pass 2 (blocks <1024) + input-projection GEMM (blocks >=1024) ----------------
// bucket2: single LDS pass — staged segment read once (4 B/entry), node-permuted in LDS
// (128 bins), written out coalesced. Per-node int2 ranges. Final edges 4 B: src(16) | w9.
// gemm blocks (independent) hide bucket latency.

__global__ __launch_bounds__(256) void b2g(const int* __restrict__ b_cur, const int* __restrict__ b_staged,
                                           int2* __restrict__ b_rng, int* __restrict__ b_edges,
                                           const int* __restrict__ l_cur, const int* __restrict__ l_staged,
                                           int2* __restrict__ l_rng, int* __restrict__ l_edges,
                                           const float* __restrict__ Ab, const float* __restrict__ Al,
                                           const ushort* __restrict__ Wt,
                                           const float* __restrict__ biasb, const float* __restrict__ biasl,
                                           ushort* __restrict__ Yb, ushort* __restrict__ Yl) {
    __shared__ __align__(16) char smem[52224];  // union: {seg|ord|segd} or {As|Bs}
    __shared__ int cnt[128], curs[128], wt2[2];
    const int t = threadIdx.x;
    const int bid = blockIdx.x;
    if (bid < 1024) {
        const int g = bid >> 9;
        const int b = bid & 511;
        const int* bcur = g ? l_cur : b_cur;
        const int* staged = g ? l_staged : b_staged;
        int2* rng = g ? l_rng : b_rng;
        int* edges = g ? l_edges : b_edges;
        const int s0 = b * CAP;
        int len = bcur[b] - s0;
        if (len > CAP) len = CAP;  // overflow guard (P ~ 1e-12)
        if (t < 128) cnt[t] = 0;
        __syncthreads();
        int* seg = (int*)smem;
        int* ord = (int*)(smem + CAP * 4);
        unsigned char* segd = (unsigned char*)(smem + CAP * 8);
        for (int i = t; i < len; i += 256) {
            int v = staged[s0 + i];
            int dl = (v >> 16) & 127;
            unsigned wq = ((unsigned)v) >> 23;
            seg[i] = (int)(((unsigned)v & 0xffffu) | (wq << 16));
            segd[i] = (unsigned char)dl;
            atomicAdd(&cnt[dl], 1);
        }
        __syncthreads();
        int v = 0, inc = 0;
        if (t < 128) {
            v = cnt[t];
            inc = v;
            for (int o = 1; o < 64; o <<= 1) { int x = __shfl_up(inc, o); if ((t & 63) >= o) inc += x; }
            if ((t & 63) == 63) wt2[t >> 6] = inc;
        }
        __syncthreads();
        if (t < 128) {
            int excl = inc - v + (t >= 64 ? wt2[0] : 0);
            curs[t] = excl;
            rng[b * 128 + t] = make_int2(s0 + excl, s0 + excl + v);
        }
        __syncthreads();
        for (int i = t; i < len; i += 256) {
            int p = atomicAdd(&curs[segd[i]], 1);
            ord[p] = seg[i];
        }
        __syncthreads();
        for (int i = t; i < len; i += 256)
            edges[s0 + i] = ord[i];
    } else {
        // input-projection GEMM (fp32 A -> bf16 Y), proven R8 tile
        ushort* As = (ushort*)smem;                       // 64 x ASTRIDE
        ushort* Bs = (ushort*)(smem + 64 * ASTRIDE * 2);  // 128 x ASTRIDE
        const int bid2 = bid - 1024;
        const int g = bid2 >> 10;
        const float* A = g ? Al : Ab;
        const ushort* W = Wt + (size_t)g * 16384;
        const float* bias = g ? biasl : biasb;
        ushort* Y = g ? Yl : Yb;
        const int r0 = (bid2 & 1023) * 64;

#pragma unroll
        for (int p = 0; p < 8; ++p) {
            int c = p * 256 + t;
            int row = c >> 5, o4 = (c & 31) * 4;
            float4 v = *(const float4*)(A + (size_t)(r0 + row) * 128 + o4);
            ushort4 u;
            u.x = f2bf(v.x); u.y = f2bf(v.y); u.z = f2bf(v.z); u.w = f2bf(v.w);
            *(ushort4*)&As[row * ASTRIDE + o4] = u;
        }
#pragma unroll
        for (int p = 0; p < 8; ++p) {
            int c = p * 256 + t;
            int n = c >> 4, o8 = (c & 15) * 8;
            *(uint4*)&Bs[n * ASTRIDE + o8] = *(const uint4*)(W + n * 128 + o8);
        }
        __syncthreads();

        const int lane = t & 63;
        const int w = t >> 6;
        const int wm = (w & 1) * 32;
        const int wn = (w >> 1) * 64;
        const int q = lane >> 4;
        const int l16 = lane & 15;

        ffrag acc[2][4];
#pragma unroll
        for (int mt = 0; mt < 2; ++mt)
#pragma unroll
            for (int nt = 0; nt < 4; ++nt) acc[mt][nt] = (ffrag){0.f, 0.f, 0.f, 0.f};

#pragma unroll
        for (int kc = 0; kc < 4; ++kc) {
            bfrag a[2], b[4];
#pragma unroll
            for (int mt = 0; mt < 2; ++mt)
                a[mt] = *(const bfrag*)&As[(wm + mt * 16 + l16) * ASTRIDE + kc * 32 + q * 8];
#pragma unroll
            for (int nt = 0; nt < 4; ++nt)
                b[nt] = *(const bfrag*)&Bs[(wn + nt * 16 + l16) * ASTRIDE + kc * 32 + q * 8];
#pragma unroll
            for (int mt = 0; mt < 2; ++mt)
#pragma unroll
                for (int nt = 0; nt < 4; ++nt)
                    acc[mt][nt] = __builtin_amdgcn_mfma_f32_16x16x32_bf16(a[mt], b[nt], acc[mt][nt], 0, 0, 0);
        }

        float bias_v[4];
#pragma unroll
        for (int nt = 0; nt < 4; ++nt) bias_v[nt] = bias[wn + nt * 16 + l16];
#pragma unroll
        for (int mt = 0; mt < 2; ++mt)
#pragma unroll
            for (int nt = 0; nt < 4; ++nt)
#pragma unroll
                for (int r = 0; r < 4; ++r) {
                    int row = r0 + wm + mt * 16 + q * 4 + r;
                    int col = wn + nt * 16 + l16;
                    float v = fmaxf(acc[mt][nt][r] + bias_v[nt], 0.f);
                    Y[(size_t)row * 128 + col] = f2bf(v);
                }
    }
}

// ---------------- layer GEMM (bf16 A, optional alpha-mix in staging) ----------------

template <bool MIX>
__global__ __launch_bounds__(256) void gemm_layer(const ushort* __restrict__ A, const ushort* __restrict__ A2,
                                                  const int* __restrict__ ridx,
                                                  const ushort* __restrict__ Wt, const float* __restrict__ bias,
                                                  ushort* __restrict__ Y) {
    __shared__ ushort As[64 * ASTRIDE];
    __shared__ ushort Bs[128 * ASTRIDE];
    const int tid = threadIdx.x;
    const int r0 = blockIdx.x * 64;

#pragma unroll
    for (int p = 0; p < 4; ++p) {
        int c = p * 256 + tid;
        int row = c >> 4, o8 = (c & 15) * 8;
        uint4 v = *(const uint4*)(A + (size_t)(r0 + row) * 128 + o8);
        if (MIX) {
            int rr = ridx[r0 + row];
            uint4 v2 = *(const uint4*)(A2 + (size_t)rr * 128 + o8);
            uint4 o;
            float x0, x1;
            x0 = 0.9f * bflo(v.x) + 0.1f * bflo(v2.x);
            x1 = 0.9f * bfhi(v.x) + 0.1f * bfhi(v2.x);
            o.x = (unsigned)f2bf(x0) | ((unsigned)f2bf(x1) << 16);
            x0 = 0.9f * bflo(v.y) + 0.1f * bflo(v2.y);
            x1 = 0.9f * bfhi(v.y) + 0.1f * bfhi(v2.y);
            o.y = (unsigned)f2bf(x0) | ((unsigned)f2bf(x1) << 16);
            x0 = 0.9f * bflo(v.z) + 0.1f * bflo(v2.z);
            x1 = 0.9f * bfhi(v.z) + 0.1f * bfhi(v2.z);
            o.z = (unsigned)f2bf(x0) | ((unsigned)f2bf(x1) << 16);
            x0 = 0.9f * bflo(v.w) + 0.1f * bflo(v2.w);
            x1 = 0.9f * bfhi(v.w) + 0.1f * bfhi(v2.w);
            o.w = (unsigned)f2bf(x0) | ((unsigned)f2bf(x1) << 16);
            v = o;
        }
        *(uint4*)&As[row * ASTRIDE + o8] = v;
    }
#pragma unroll
    for (int p = 0; p < 8; ++p) {
        int c = p * 256 + tid;
        int n = c >> 4, o8 = (c & 15) * 8;
        *(uint4*)&Bs[n * ASTRIDE + o8] = *(const uint4*)(Wt + n * 128 + o8);
    }
    __syncthreads();

    const int lane = tid & 63;
    const int w = tid >> 6;
    const int wm = (w & 1) * 32;
    const int wn = (w >> 1) * 64;
    const int q = lane >> 4;
    const int l16 = lane & 15;

    ffrag acc[2][4];
#pragma unroll
    for (int mt = 0; mt < 2; ++mt)
#pragma unroll
        for (int nt = 0; nt < 4; ++nt) acc[mt][nt] = (ffrag){0.f, 0.f, 0.f, 0.f};

#pragma unroll
    for (int kc = 0; kc < 4; ++kc) {
        bfrag a[2], b[4];
#pragma unroll
        for (int mt = 0; mt < 2; ++mt)
            a[mt] = *(const bfrag*)&As[(wm + mt * 16 + l16) * ASTRIDE + kc * 32 + q * 8];
#pragma unroll
        for (int nt = 0; nt < 4; ++nt)
            b[nt] = *(const bfrag*)&Bs[(wn + nt * 16 + l16) * ASTRIDE + kc * 32 + q * 8];
#pragma unroll
        for (int mt = 0; mt < 2; ++mt)
#pragma unroll
            for (int nt = 0; nt < 4; ++nt)
                acc[mt][nt] = __builtin_amdgcn_mfma_f32_16x16x32_bf16(a[mt], b[nt], acc[mt][nt], 0, 0, 0);
    }

    float bias_v[4];
#pragma unroll
    for (int nt = 0; nt < 4; ++nt) bias_v[nt] = bias[wn + nt * 16 + l16];
#pragma unroll
    for (int mt = 0; mt < 2; ++mt)
#pragma unroll
        for (int nt = 0; nt < 4; ++nt)
#pragma unroll
            for (int r = 0; r < 4; ++r) {
                int row = r0 + wm + mt * 16 + q * 4 + r;
                int col = wn + nt * 16 + l16;
                float v = fmaxf(acc[mt][nt][r] + bias_v[nt], 0.f);
                Y[(size_t)row * 128 + col] = f2bf(v);
            }
}

// ---------------- SpMM: half-wave per dst node, 4-B packed edges, both graphs per dispatch ----------------
// Proven round-4 inner loop + round-9 software-pipelined edge loads. This structure is the
// measured floor: byte cuts (r4), src ordering (r8), dual-node MLP (r10), NT loads (r11),
// and GEMM overlap (r12) all failed to improve it.

#define PROC8(pA, pB)                                                                          \
    {                                                                                          \
        ushort4 v0 = *(const ushort4*)(X + ((size_t)((unsigned)pA.x & 0xffffu) << 7) + f);     \
        ushort4 v1 = *(const ushort4*)(X + ((size_t)((unsigned)pA.y & 0xffffu) << 7) + f);     \
        ushort4 v2 = *(const ushort4*)(X + ((size_t)((unsigned)pA.z & 0xffffu) << 7) + f);     \
        ushort4 v3 = *(const ushort4*)(X + ((size_t)((unsigned)pA.w & 0xffffu) << 7) + f);     \
        ushort4 v4 = *(const ushort4*)(X + ((size_t)((unsigned)pB.x & 0xffffu) << 7) + f);     \
        ushort4 v5 = *(const ushort4*)(X + ((size_t)((unsigned)pB.y & 0xffffu) << 7) + f);     \
        ushort4 v6 = *(const ushort4*)(X + ((size_t)((unsigned)pB.z & 0xffffu) << 7) + f);     \
        ushort4 v7 = *(const ushort4*)(X + ((size_t)((unsigned)pB.w & 0xffffu) << 7) + f);     \
        float w0 = (float)((unsigned)pA.x >> 16) * WDEC;                                       \
        float w1 = (float)((unsigned)pA.y >> 16) * WDEC;                                       \
        float w2 = (float)((unsigned)pA.z >> 16) * WDEC;                                       \
        float w3 = (float)((unsigned)pA.w >> 16) * WDEC;                                       \
        float w4 = (float)((unsigned)pB.x >> 16) * WDEC;                                       \
        float w5 = (float)((unsigned)pB.y >> 16) * WDEC;                                       \
        float w6 = (float)((unsigned)pB.z >> 16) * WDEC;                                       \
        float w7 = (float)((unsigned)pB.w >> 16) * WDEC;                                       \
        a0 += w0 * bf2f(v0.x) + w1 * bf2f(v1.x) + w2 * bf2f(v2.x) + w3 * bf2f(v3.x)            \
            + w4 * bf2f(v4.x) + w5 * bf2f(v5.x) + w6 * bf2f(v6.x) + w7 * bf2f(v7.x);           \
        a1 += w0 * bf2f(v0.y) + w1 * bf2f(v1.y) + w2 * bf2f(v2.y) + w3 * bf2f(v3.y)            \
            + w4 * bf2f(v4.y) + w5 * bf2f(v5.y) + w6 * bf2f(v6.y) + w7 * bf2f(v7.y);           \
        a2 += w0 * bf2f(v0.z) + w1 * bf2f(v1.z) + w2 * bf2f(v2.z) + w3 * bf2f(v3.z)            \
            + w4 * bf2f(v4.z) + w5 * bf2f(v5.z) + w6 * bf2f(v6.z) + w7 * bf2f(v7.z);           \
        a3 += w0 * bf2f(v0.w) + w1 * bf2f(v1.w) + w2 * bf2f(v2.w) + w3 * bf2f(v3.w)            \
            + w4 * bf2f(v4.w) + w5 * bf2f(v5.w) + w6 * bf2f(v6.w) + w7 * bf2f(v7.w);           \
    }

__global__ __launch_bounds__(256) void spmm2(const int2* __restrict__ bs_rng, const int* __restrict__ bs_edges,
                                             const ushort* __restrict__ Xb, ushort* __restrict__ Yb,
                                             const int2* __restrict__ ls_rng, const int* __restrict__ ls_edges,
                                             const ushort* __restrict__ Xl, ushort* __restrict__ Yl) {
    const int g = blockIdx.x & 1;
    const int2* rng = g ? ls_rng : bs_rng;
    const int* edges = g ? ls_edges : bs_edges;
    const ushort* X = g ? Xl : Xb;
    ushort* Y = g ? Yl : Yb;
    int node = (((blockIdx.x >> 1) * 256) + threadIdx.x) >> 5;
    int lane = threadIdx.x & 31;
    int2 r = rng[node];
    int s0 = r.x;
    int s1 = r.y;
    const int f = lane * 4;
    float a0 = 0.f, a1 = 0.f, a2 = 0.f, a3 = 0.f;
    int e = s0;
    // head: align e to 4 for int4 edge loads
    for (; e < s1 && (e & 3); ++e) {
        unsigned pe = (unsigned)edges[e];
        float w = (float)(pe >> 16) * WDEC;
        ushort4 v = *(const ushort4*)(X + ((size_t)(pe & 0xffffu) << 7) + f);
        a0 += w * bf2f(v.x); a1 += w * bf2f(v.y); a2 += w * bf2f(v.z); a3 += w * bf2f(v.w);
    }
    if (e + 8 <= s1) {
        int4 pA = *(const int4*)(edges + e);
        int4 pB = *(const int4*)(edges + e + 4);
        for (; e + 16 <= s1; e += 8) {
            int4 nA = *(const int4*)(edges + e + 8);   // prefetch next iter's edges
            int4 nB = *(const int4*)(edges + e + 12);
            PROC8(pA, pB);
            pA = nA;
            pB = nB;
        }
        PROC8(pA, pB);
        e += 8;
    }
    for (; e + 4 <= s1; e += 4) {
        int4 pA = *(const int4*)(edges + e);
        ushort4 v0 = *(const ushort4*)(X + ((size_t)((unsigned)pA.x & 0xffffu) << 7) + f);
        ushort4 v1 = *(const ushort4*)(X + ((size_t)((unsigned)pA.y & 0xffffu) << 7) + f);
        ushort4 v2 = *(const ushort4*)(X + ((size_t)((unsigned)pA.z & 0xffffu) << 7) + f);
        ushort4 v3 = *(const ushort4*)(X + ((size_t)((unsigned)pA.w & 0xffffu) << 7) + f);
        float w0 = (float)((unsigned)pA.x >> 16) * WDEC;
        float w1 = (float)((unsigned)pA.y >> 16) * WDEC;
        float w2 = (float)((unsigned)pA.z >> 16) * WDEC;
        float w3 = (float)((unsigned)pA.w >> 16) * WDEC;
        a0 += w0 * bf2f(v0.x) + w1 * bf2f(v1.x) + w2 * bf2f(v2.x) + w3 * bf2f(v3.x);
        a1 += w0 * bf2f(v0.y) + w1 * bf2f(v1.y) + w2 * bf2f(v2.y) + w3 * bf2f(v3.y);
        a2 += w0 * bf2f(v0.z) + w1 * bf2f(v1.z) + w2 * bf2f(v2.z) + w3 * bf2f(v3.z);
        a3 += w0 * bf2f(v0.w) + w1 * bf2f(v1.w) + w2 * bf2f(v2.w) + w3 * bf2f(v3.w);
    }
    for (; e < s1; ++e) {
        unsigned pe = (unsigned)edges[e];
        float w = (float)(pe >> 16) * WDEC;
        ushort4 v = *(const ushort4*)(X + ((size_t)(pe & 0xffffu) << 7) + f);
        a0 += w * bf2f(v.x); a1 += w * bf2f(v.y); a2 += w * bf2f(v.z); a3 += w * bf2f(v.w);
    }
    ushort4 o;
    o.x = f2bf(a0);
    o.y = f2bf(a1);
    o.z = f2bf(a2);
    o.w = f2bf(a3);
    *(ushort4*)(Y + (size_t)node * 128 + f) = o;
}

// ---------------- pooling: segment sums over gid-sorted entries (fixed-capacity regions) ----------------

__global__ __launch_bounds__(256) void pool_accum(const int* __restrict__ p_cur, const int* __restrict__ sorted_idx,
                                                  const ushort* __restrict__ X, float* __restrict__ gsum) {
    const int g = blockIdx.x >> 5;
    const int sgm = blockIdx.x & 31;
    const int gs = g * PCAP;
    const int cnt = p_cur[g] - gs;
    const int e_begin = gs + ((cnt * sgm) >> 5);
    const int e_end = gs + ((cnt * (sgm + 1)) >> 5);
    const int t = threadIdx.x;
    const int fp = t & 63;
    const int sub = t >> 6;
    float ax = 0.f, ay = 0.f;
#pragma unroll 4
    for (int e = e_begin + sub; e < e_end; e += 4) {
        int idx = sorted_idx[e];
        ushort2 u = *(const ushort2*)(X + (size_t)idx * 128 + fp * 2);
        ax += bf2f(u.x);
        ay += bf2f(u.y);
    }
    __shared__ float sx[256], sy[256];
    sx[t] = ax;
    sy[t] = ay;
    __syncthreads();
    if (t < 64) {
        atomicAdd(&gsum[g * 128 + fp * 2 + 0], sx[t] + sx[t + 64] + sx[t + 128] + sx[t + 192]);
        atomicAdd(&gsum[g * 128 + fp * 2 + 1], sy[t] + sy[t + 64] + sy[t + 128] + sy[t + 192]);
    }
}

// ---------------- final: out = (gsum/cnt) @ Wp + bp, 64x2 ----------------

__global__ __launch_bounds__(128) void final_kernel(const float* __restrict__ gsum, const int* __restrict__ p_cur,
                                                    const float* __restrict__ Wp, const float* __restrict__ bp,
                                                    float* __restrict__ out) {
    int t = threadIdx.x;
    int g = t >> 1;
    int o = t & 1;
    float cnt = (float)(p_cur[g] - g * PCAP);
    float inv = 1.f / fmaxf(cnt, 1.f);
    float acc = bp[o];
    for (int f = 0; f < 128; ++f) acc += gsum[g * 128 + f] * inv * Wp[f * 2 + o];
    out[g * 2 + o] = acc;
}

// ---------------- launch ----------------

extern "C" void kernel_launch(void* const* d_in, const int* in_sizes, int n_in,
                              void* d_out, int out_size, void* d_ws, size_t ws_size,
                              hipStream_t stream) {
    const float* x              = (const float*)d_in[0];
    const int*   edge_index     = (const int*)d_in[1];
    const float* edge_weight    = (const float*)d_in[2];
    const float* local_x0       = (const float*)d_in[3];
    const int*   copy2orig      = (const int*)d_in[4];
    const int*   local_adj_idx  = (const int*)d_in[5];
    const float* local_adj_val  = (const float*)d_in[6];
    const int*   memb_idx       = (const int*)d_in[7];
    const int*   memb_gid       = (const int*)d_in[8];
    const float* Wb_in          = (const float*)d_in[10];
    const float* bb_in          = (const float*)d_in[11];
    const float* Wl_in          = (const float*)d_in[12];
    const float* bl_in          = (const float*)d_in[13];
    const float* W_base         = (const float*)d_in[14];
    const float* b_base         = (const float*)d_in[15];
    const float* W_local        = (const float*)d_in[16];
    const float* b_local        = (const float*)d_in[17];
    const float* Wp             = (const float*)d_in[18];
    const float* bp             = (const float*)d_in[19];
    float* out = (float*)d_out;

    constexpr int N = 65536, M = 65536, E = 1048576, EL = 1048576, K = 131072, H = 128;

    char* wsb = (char*)d_ws;
    size_t off = 0;
    auto alloc = [&](size_t bytes) -> char* {
        char* p = wsb + off;
        off += (bytes + 255) & ~(size_t)255;
        return p;
    };
    int2*   bs_rng   = (int2*)alloc((size_t)N * 8);
    int*    bs_edges = (int*)alloc((size_t)NB * CAP * 4 + 64);
    int*    bs_stage = (int*)alloc((size_t)NB * CAP * 4);
    int*    bs_cur   = (int*)alloc(NB * 4);
    int2*   ls_rng   = (int2*)alloc((size_t)M * 8);
    int*    ls_edges = (int*)alloc((size_t)NB * CAP * 4 + 64);
    int*    ls_stage = (int*)alloc((size_t)NB * CAP * 4);
    int*    ls_cur   = (int*)alloc(NB * 4);
    ushort* bufA     = (ushort*)alloc((size_t)N * H * 2);
    ushort* bufB     = (ushort*)alloc((size_t)M * H * 2);
    ushort* bufC     = (ushort*)alloc((size_t)N * H * 2);
    ushort* bufD     = (ushort*)alloc((size_t)M * H * 2);
    ushort* wt       = (ushort*)alloc((size_t)6 * 16384 * 2);
    int*    p_cursor = (int*)alloc(64 * 4);
    int*    p_sorted = (int*)alloc((size_t)64 * PCAP * 4);
    float*  pool_sum = (float*)alloc(64 * 128 * 4);

    const int* b_src = edge_index;
    const int* b_dst = edge_index + E;
    const int* l_src = local_adj_idx;
    const int* l_dst = local_adj_idx + EL;

    // weight prep + fixed-capacity cursor init (one dispatch; no histogram pre-pass needed)
    wprep_zero<<<416, 256, 0, stream>>>(Wb_in, Wl_in, W_base, W_local, wt,
                                        bs_cur, ls_cur, p_cursor, (int*)pool_sum);

    // bucket pass 1 (both graphs, 4-B staged entries) || pool counting-sort scatter
    b1p<<<1152, 512, 0, stream>>>(b_src, b_dst, edge_weight, bs_cur, bs_stage,
                                  l_src, l_dst, local_adj_val, ls_cur, ls_stage,
                                  memb_idx, memb_gid, p_cursor, p_sorted);

    // bucket pass 2 (single LDS pass) || input-projection GEMMs
    b2g<<<3072, 256, 0, stream>>>(bs_cur, bs_stage, bs_rng, bs_edges,
                                  ls_cur, ls_stage, ls_rng, ls_edges,
                                  x, local_x0, wt, bb_in, bl_in, bufA, bufB);

    // layers: fused spmm dispatch (both graphs), then base gemm, then local gemm (mix)
    for (int l = 0; l < 2; ++l) {
        spmm2<<<16384, 256, 0, stream>>>(bs_rng, bs_edges, bufA, bufC,
                                         ls_rng, ls_edges, bufB, bufD);
        gemm_layer<false><<<N / 64, 256, 0, stream>>>(bufC, nullptr, nullptr,
                                                      wt + (size_t)(2 + l) * 16384, b_base + (size_t)l * H, bufA);
        gemm_layer<true><<<M / 64, 256, 0, stream>>>(bufD, bufA, copy2orig,
                                                     wt + (size_t)(4 + l) * 16384, b_local + (size_t)l * H, bufB);
    }

    // pooling + final projection
    pool_accum<<<64 * 32, 256, 0, stream>>>(p_cursor, p_sorted, bufB, pool_sum);
    final_kernel<<<1, 128, 0, stream>>>(pool_sum, p_cursor, Wp, bp, out);
}